// Round 12
// baseline (92.613 us; speedup 1.0000x reference)
//
#include <hip/hip_runtime.h>
#include <stdint.h>

#define PP     16
#define LRDIM  256
#define DDIM   1024
#define LN_EPS 1e-5f

typedef __attribute__((ext_vector_type(8))) short  short8;
typedef __attribute__((ext_vector_type(4))) float  f32x4;

__device__ __forceinline__ uint32_t bf16_rne(float f) {
    uint32_t u = __builtin_bit_cast(uint32_t, f);
    return (u + 0x7fffu + ((u >> 16) & 1u)) >> 16;
}
__device__ __forceinline__ float bf_lo(uint32_t u) {
    return __builtin_bit_cast(float, u << 16);
}
__device__ __forceinline__ float bf_hi(uint32_t u) {
    return __builtin_bit_cast(float, u & 0xffff0000u);
}

// ---------------------------------------------------------------------------
// K1 fused prep (unchanged, proven r5-r11).
// blocks [0,512):  table2b[p][c][j] = bf16(sum_i pe[p][i][j] * bt[c][i])
// blocks [512,640): repack W_up -> bf16 MFMA B-frags, KS-MAJOR:
//                  wb[((ks*64)+nfg)*64 + l] = W[nfg*16+(l&15)][ks*32+(l>>4)*8+..7]
// ---------------------------------------------------------------------------
__global__ __launch_bounds__(256) void k_prep(const float* __restrict__ bt,
                                              const float* __restrict__ pe,
                                              const float* __restrict__ W,
                                              unsigned short* __restrict__ t2b,
                                              uint4* __restrict__ wb) {
    if (blockIdx.x < 512) {
        const int p  = blockIdx.x >> 5;          // 0..15
        const int c0 = (blockIdx.x & 31) << 3;   // 0..248
        const int j  = threadIdx.x;
        const float* pep = pe + (size_t)p * LRDIM * LRDIM;
        float a[8];
#pragma unroll
        for (int r = 0; r < 8; ++r) a[r] = 0.f;
#pragma unroll 4
        for (int i = 0; i < LRDIM; ++i) {
            const float v = pep[i * LRDIM + j];          // coalesced across j
#pragma unroll
            for (int r = 0; r < 8; ++r)                   // uniform -> s_loads
                a[r] = fmaf(v, bt[(c0 + r) * LRDIM + i], a[r]);
        }
#pragma unroll
        for (int r = 0; r < 8; ++r)
            t2b[(size_t)((p << 8) + c0 + r) * LRDIM + j] =
                (unsigned short)bf16_rne(a[r]);
    } else {
        const int gt  = (blockIdx.x - 512) * 256 + threadIdx.x;  // 0..32767
        const int l   = gt & 63;
        const int ks  = (gt >> 6) & 7;
        const int nfg = gt >> 9;                                  // 0..63
        const int n   = nfg * 16 + (l & 15);
        const int k   = ks * 32 + (l >> 4) * 8;
        const float* src = W + (size_t)n * LRDIM + k;
        uint32_t r[4];
#pragma unroll
        for (int q = 0; q < 4; ++q) {
            const uint32_t lo = bf16_rne(src[2 * q + 0]);
            const uint32_t hi = bf16_rne(src[2 * q + 1]);
            r[q] = lo | (hi << 16);
        }
        wb[((ks << 6) + nfg) * 64 + l] = make_uint4(r[0], r[1], r[2], r[3]);
    }
}

// ---------------------------------------------------------------------------
// K2: gather-sum (r5 proven). One wave per token; lane owns lr = 4l..4l+3.
// A[tok][256] bf16 out, linear.
// ---------------------------------------------------------------------------
__global__ __launch_bounds__(256) void k_gather(const int* __restrict__ ids,
                                                const unsigned short* __restrict__ t2b,
                                                uint2* __restrict__ Aq,
                                                int ntok) {
    const int wid = (blockIdx.x << 2) + (threadIdx.x >> 6);
    const int l   = threadIdx.x & 63;
    if (wid >= ntok) return;

    const int myid = (l < PP) ? ids[(size_t)wid * PP + l] : -1;

    float a0 = 0.f, a1 = 0.f, a2 = 0.f, a3 = 0.f;
#pragma unroll
    for (int p = 0; p < PP; ++p) {
        const int   id  = __shfl(myid, p);
        const float msk = (id >= 0) ? 1.f : 0.f;
        const uint2 v = *(const uint2*)(t2b +
                          ((size_t)((p << 8) + (id & 255)) << 8) + (l << 2));
        a0 = fmaf(msk, bf_lo(v.x), a0);
        a1 = fmaf(msk, bf_hi(v.x), a1);
        a2 = fmaf(msk, bf_lo(v.y), a2);
        a3 = fmaf(msk, bf_hi(v.y), a3);
    }
    uint2 pk;
    pk.x = bf16_rne(a0) | (bf16_rne(a1) << 16);
    pk.y = bf16_rne(a2) | (bf16_rne(a3) << 16);
    Aq[((size_t)wid << 6) + l] = pk;
}

// ---------------------------------------------------------------------------
// K3: GEMM with B ENTIRELY IN REGISTERS; writes x = A@W^T + b as bf16.
// Grid = 512 token-tiles x 2 col-halves = 1024 blocks, 512 thr (8 waves).
// Wave w owns 64 cols [h*512 + w*64 ...): its full B slice = 4 nf x 8 ks
// uint4 = 128 VGPRs, loaded ONCE -> the K-loop has ZERO global loads
// (A-frag reads from L2 + MFMA only). acc[2][4] = 32 regs (AGPR).
// NO LDS, no barriers; ~170 regs under the (512,2)=256 budget -> up to
// 4 blocks/CU resident = 32 waves/CU of TLP (vs 8-16 in r2-r11).
// ---------------------------------------------------------------------------
__global__ __launch_bounds__(512, 2) void k_gemmB(const unsigned short* __restrict__ A,
                                                  const uint4* __restrict__ wb,
                                                  const float* __restrict__ b_up,
                                                  unsigned short* __restrict__ x16,
                                                  int ntok) {
    const int t    = threadIdx.x;
    const int w    = t >> 6;        // wave 0..7
    const int l    = t & 63;
    const int lo4  = l & 15;
    const int hi2  = l >> 4;        // 0..3
    const int tile = blockIdx.x >> 1;
    const int h    = blockIdx.x & 1;
    const int tok0 = tile << 5;

    // ---- load whole B slice once: breg[ks*4+nf], static indices only ----
    uint4 breg[32];
    const uint4* wp = wb + ((size_t)((h << 5) + (w << 2)) << 6) + l;
#pragma unroll
    for (int ks = 0; ks < 8; ++ks)
#pragma unroll
        for (int nf = 0; nf < 4; ++nf)
            breg[ks * 4 + nf] = wp[(size_t)((ks << 6) + nf) << 6];

    f32x4 acc[2][4];
#pragma unroll
    for (int m2 = 0; m2 < 2; ++m2)
#pragma unroll
        for (int nf = 0; nf < 4; ++nf) {
            f32x4 z = {0.f, 0.f, 0.f, 0.f};
            acc[m2][nf] = z;
        }

    // ---- K-loop: pure A-read + MFMA ----
    const unsigned short* Abase = A + ((size_t)tok0 << 8);
#pragma unroll
    for (int ks = 0; ks < 8; ++ks) {
        const short8 af0 = *(const short8*)(Abase + ((size_t)lo4 << 8) +
                                            (ks << 5) + (hi2 << 3));
        const short8 af1 = *(const short8*)(Abase + ((size_t)(16 + lo4) << 8) +
                                            (ks << 5) + (hi2 << 3));
#pragma unroll
        for (int nf = 0; nf < 4; ++nf) {
            const short8 bfr = __builtin_bit_cast(short8, breg[ks * 4 + nf]);
            acc[0][nf] = __builtin_amdgcn_mfma_f32_16x16x32_bf16(af0, bfr, acc[0][nf], 0, 0, 0);
            acc[1][nf] = __builtin_amdgcn_mfma_f32_16x16x32_bf16(af1, bfr, acc[1][nf], 0, 0, 0);
        }
    }

    // ---- +bias, pack bf16, store x (r5-verified C/D mapping) ----
#pragma unroll
    for (int nf = 0; nf < 4; ++nf) {
        const int col = (h << 9) + (w << 6) + (nf << 4) + lo4;
        const float bu = b_up[col];
#pragma unroll
        for (int m2 = 0; m2 < 2; ++m2) {
            const f32x4 v = acc[m2][nf];
#pragma unroll
            for (int r = 0; r < 4; ++r) {
                const int tok = tok0 + (m2 << 4) + (hi2 << 2) + r;
                if (tok < ntok)
                    x16[((size_t)tok << 10) + col] =
                        (unsigned short)bf16_rne(v[r] + bu);
            }
        }
    }
}

// ---------------------------------------------------------------------------
// K4: rowwise LayerNorm, streaming. One wave per row (4 rows / 256-thr block).
// Lane covers cols {q*256 + l*4 .. +3 : q=0..3} -> all loads/stores coalesced.
// ---------------------------------------------------------------------------
__global__ __launch_bounds__(256) void k_ln(const unsigned short* __restrict__ x16,
                                            const float* __restrict__ gamma,
                                            const float* __restrict__ beta,
                                            float* __restrict__ out,
                                            int ntok) {
    const int row = (blockIdx.x << 2) + (threadIdx.x >> 6);
    const int l   = threadIdx.x & 63;
    if (row >= ntok) return;

    const unsigned short* xr = x16 + ((size_t)row << 10);
    float v[16];
#pragma unroll
    for (int q = 0; q < 4; ++q) {
        const uint2 u = *(const uint2*)(xr + (q << 8) + (l << 2));
        v[q * 4 + 0] = bf_lo(u.x);
        v[q * 4 + 1] = bf_hi(u.x);
        v[q * 4 + 2] = bf_lo(u.y);
        v[q * 4 + 3] = bf_hi(u.y);
    }
    float s = 0.f, ss = 0.f;
#pragma unroll
    for (int k = 0; k < 16; ++k) { s += v[k]; ss += v[k] * v[k]; }
#pragma unroll
    for (int off = 1; off < 64; off <<= 1) {
        s  += __shfl_xor(s, off);
        ss += __shfl_xor(ss, off);
    }
    const float mu  = s * (1.f / DDIM);
    const float var = ss * (1.f / DDIM) - mu * mu;
    const float inv = rsqrtf(var + LN_EPS);

    float* orow = out + ((size_t)row << 10);
#pragma unroll
    for (int q = 0; q < 4; ++q) {
        const float4 g  = ((const float4*)gamma)[(q << 6) + l];
        const float4 be = ((const float4*)beta)[(q << 6) + l];
        float4 o;
        o.x = (v[q * 4 + 0] - mu) * inv * g.x + be.x;
        o.y = (v[q * 4 + 1] - mu) * inv * g.y + be.y;
        o.z = (v[q * 4 + 2] - mu) * inv * g.z + be.z;
        o.w = (v[q * 4 + 3] - mu) * inv * g.w + be.w;
        ((float4*)orow)[(q << 6) + l] = o;
    }
}

// ---------------------------------------------------------------------------
extern "C" void kernel_launch(void* const* d_in, const int* in_sizes, int n_in,
                              void* d_out, int out_size, void* d_ws, size_t ws_size,
                              hipStream_t stream) {
    const int*   ids   = (const int*)  d_in[0];
    const float* bt    = (const float*)d_in[1];
    const float* pe    = (const float*)d_in[2];
    const float* W     = (const float*)d_in[3];
    const float* b_up  = (const float*)d_in[4];
    const float* gamma = (const float*)d_in[5];
    const float* beta  = (const float*)d_in[6];
    float* out = (float*)d_out;

    const int ntok = in_sizes[0] / PP;   // B*S = 16384

    char* ws = (char*)d_ws;              // ws_size = 256 MB (observed r5 poison)
    unsigned short* t2b = (unsigned short*)(ws);              // 2 MB
    uint4*          wbb = (uint4*)(ws + (2  << 20));          // 512 KB (ks-major)
    unsigned short* Abf = (unsigned short*)(ws + (3  << 20)); // 8 MB
    uint2*          Aq  = (uint2*)Abf;
    unsigned short* x16 = (unsigned short*)(ws + (11 << 20)); // 33.5 MB

    hipLaunchKernelGGL(k_prep, dim3(640), dim3(256), 0, stream, bt, pe, W, t2b, wbb);
    hipLaunchKernelGGL(k_gather, dim3((ntok + 3) / 4), dim3(256), 0, stream,
                       ids, t2b, Aq, ntok);
    hipLaunchKernelGGL(k_gemmB, dim3((ntok + 31) / 32 * 2), dim3(512), 0, stream,
                       Abf, wbb, b_up, x16, ntok);
    hipLaunchKernelGGL(k_ln, dim3((ntok + 3) / 4), dim3(256), 0, stream,
                       x16, gamma, beta, out, ntok);
}

// Round 13
// 79.518 us; speedup vs baseline: 1.1647x; 1.1647x over previous
//
#include <hip/hip_runtime.h>
#include <stdint.h>

#define PP     16
#define LRDIM  256
#define DDIM   1024
#define LN_EPS 1e-5f

typedef __attribute__((ext_vector_type(8))) short  short8;
typedef __attribute__((ext_vector_type(4))) float  f32x4;

__device__ __forceinline__ uint32_t bf16_rne(float f) {
    uint32_t u = __builtin_bit_cast(uint32_t, f);
    return (u + 0x7fffu + ((u >> 16) & 1u)) >> 16;
}
__device__ __forceinline__ float bf_lo(uint32_t u) {
    return __builtin_bit_cast(float, u << 16);
}
__device__ __forceinline__ float bf_hi(uint32_t u) {
    return __builtin_bit_cast(float, u & 0xffff0000u);
}

// ---------------------------------------------------------------------------
// K1 fused prep (unchanged, proven r5-r12).
// blocks [0,512):  table2b[p][c][j] = bf16(sum_i pe[p][i][j] * bt[c][i])
// blocks [512,640): repack W_up -> bf16 MFMA B-frags, KS-MAJOR:
//                  wb[((ks*64)+nfg)*64 + l] = W[nfg*16+(l&15)][ks*32+(l>>4)*8+..7]
// ---------------------------------------------------------------------------
__global__ __launch_bounds__(256) void k_prep(const float* __restrict__ bt,
                                              const float* __restrict__ pe,
                                              const float* __restrict__ W,
                                              unsigned short* __restrict__ t2b,
                                              uint4* __restrict__ wb) {
    if (blockIdx.x < 512) {
        const int p  = blockIdx.x >> 5;          // 0..15
        const int c0 = (blockIdx.x & 31) << 3;   // 0..248
        const int j  = threadIdx.x;
        const float* pep = pe + (size_t)p * LRDIM * LRDIM;
        float a[8];
#pragma unroll
        for (int r = 0; r < 8; ++r) a[r] = 0.f;
#pragma unroll 4
        for (int i = 0; i < LRDIM; ++i) {
            const float v = pep[i * LRDIM + j];          // coalesced across j
#pragma unroll
            for (int r = 0; r < 8; ++r)                   // uniform -> s_loads
                a[r] = fmaf(v, bt[(c0 + r) * LRDIM + i], a[r]);
        }
#pragma unroll
        for (int r = 0; r < 8; ++r)
            t2b[(size_t)((p << 8) + c0 + r) * LRDIM + j] =
                (unsigned short)bf16_rne(a[r]);
    } else {
        const int gt  = (blockIdx.x - 512) * 256 + threadIdx.x;  // 0..32767
        const int l   = gt & 63;
        const int ks  = (gt >> 6) & 7;
        const int nfg = gt >> 9;                                  // 0..63
        const int n   = nfg * 16 + (l & 15);
        const int k   = ks * 32 + (l >> 4) * 8;
        const float* src = W + (size_t)n * LRDIM + k;
        uint32_t r[4];
#pragma unroll
        for (int q = 0; q < 4; ++q) {
            const uint32_t lo = bf16_rne(src[2 * q + 0]);
            const uint32_t hi = bf16_rne(src[2 * q + 1]);
            r[q] = lo | (hi << 16);
        }
        wb[((ks << 6) + nfg) * 64 + l] = make_uint4(r[0], r[1], r[2], r[3]);
    }
}

// ---------------------------------------------------------------------------
// K2: gather-sum (r5 proven). One wave per token; lane owns lr = 4l..4l+3.
// A[tok][256] bf16 out, linear.
// ---------------------------------------------------------------------------
__global__ __launch_bounds__(256) void k_gather(const int* __restrict__ ids,
                                                const unsigned short* __restrict__ t2b,
                                                uint2* __restrict__ Aq,
                                                int ntok) {
    const int wid = (blockIdx.x << 2) + (threadIdx.x >> 6);
    const int l   = threadIdx.x & 63;
    if (wid >= ntok) return;

    const int myid = (l < PP) ? ids[(size_t)wid * PP + l] : -1;

    float a0 = 0.f, a1 = 0.f, a2 = 0.f, a3 = 0.f;
#pragma unroll
    for (int p = 0; p < PP; ++p) {
        const int   id  = __shfl(myid, p);
        const float msk = (id >= 0) ? 1.f : 0.f;
        const uint2 v = *(const uint2*)(t2b +
                          ((size_t)((p << 8) + (id & 255)) << 8) + (l << 2));
        a0 = fmaf(msk, bf_lo(v.x), a0);
        a1 = fmaf(msk, bf_hi(v.x), a1);
        a2 = fmaf(msk, bf_lo(v.y), a2);
        a3 = fmaf(msk, bf_hi(v.y), a3);
    }
    uint2 pk;
    pk.x = bf16_rne(a0) | (bf16_rne(a1) << 16);
    pk.y = bf16_rne(a2) | (bf16_rne(a3) << 16);
    Aq[((size_t)wid << 6) + l] = pk;
}

// ---------------------------------------------------------------------------
// K3: PERSISTENT-B GEMM; writes x = A@W^T + b as bf16.
// Grid = 512 blocks = 4 col-quarters x 128 tile-groups; block = 256 thr
// (4 waves); wave owns 64 cols. B slice = breg[32] uint4 = 128 VGPRs loaded
// ONCE, then '#pragma unroll 1' runtime loop over 4 token tiles keeps breg
// LIVE (r12 lesson: without cross-tile reuse the compiler sinks each B load
// to its single use -> per-use L2 latency = 48 us). B traffic 268 -> 67 MB.
// __launch_bounds__(256,2): 256-reg cap (proven safe), ~200 used ->
// 2 blocks/CU so block-2's B-load/stores overlap block-1's MFMA.
// ---------------------------------------------------------------------------
__global__ __launch_bounds__(256, 2) void k_gemmB(const unsigned short* __restrict__ A,
                                                  const uint4* __restrict__ wb,
                                                  const float* __restrict__ b_up,
                                                  unsigned short* __restrict__ x16,
                                                  int ntok, int ntiles) {
    const int t    = threadIdx.x;
    const int w    = t >> 6;        // wave 0..3
    const int l    = t & 63;
    const int lo4  = l & 15;
    const int hi2  = l >> 4;        // 0..3
    const int qd   = blockIdx.x & 3;        // col quarter 0..3
    const int g    = blockIdx.x >> 2;       // tile group 0..127

    const int nfgb = (qd << 4) + (w << 2);  // wave's first n-fragment

    // ---- load whole B slice once: breg[ks*4+nf] (128 VGPRs) ----
    uint4 breg[32];
    const uint4* wp = wb + ((size_t)nfgb << 6) + l;
#pragma unroll
    for (int ks = 0; ks < 8; ++ks)
#pragma unroll
        for (int nf = 0; nf < 4; ++nf)
            breg[ks * 4 + nf] = wp[((size_t)ks << 12) + ((size_t)nf << 6)];

    // ---- loop-invariant bias for this lane's cols ----
    float bu[4];
#pragma unroll
    for (int nf = 0; nf < 4; ++nf)
        bu[nf] = b_up[((nfgb + nf) << 4) + lo4];

    // ---- persistent tile loop (runtime trip; breg stays resident) ----
#pragma unroll 1
    for (int tile = g; tile < ntiles; tile += 128) {
        const int tok0 = tile << 5;

        f32x4 acc[2][4];
#pragma unroll
        for (int m2 = 0; m2 < 2; ++m2)
#pragma unroll
            for (int nf = 0; nf < 4; ++nf) {
                f32x4 z = {0.f, 0.f, 0.f, 0.f};
                acc[m2][nf] = z;
            }

        const unsigned short* Abase = A + ((size_t)tok0 << 8);
#pragma unroll
        for (int ks = 0; ks < 8; ++ks) {
            const short8 af0 = *(const short8*)(Abase + ((size_t)lo4 << 8) +
                                                (ks << 5) + (hi2 << 3));
            const short8 af1 = *(const short8*)(Abase + ((size_t)(16 + lo4) << 8) +
                                                (ks << 5) + (hi2 << 3));
#pragma unroll
            for (int nf = 0; nf < 4; ++nf) {
                const short8 bfr = __builtin_bit_cast(short8, breg[ks * 4 + nf]);
                acc[0][nf] = __builtin_amdgcn_mfma_f32_16x16x32_bf16(af0, bfr, acc[0][nf], 0, 0, 0);
                acc[1][nf] = __builtin_amdgcn_mfma_f32_16x16x32_bf16(af1, bfr, acc[1][nf], 0, 0, 0);
            }
        }

        // ---- +bias, pack bf16, store x (r5-verified C/D mapping) ----
#pragma unroll
        for (int nf = 0; nf < 4; ++nf) {
            const int col = ((nfgb + nf) << 4) + lo4;
#pragma unroll
            for (int m2 = 0; m2 < 2; ++m2) {
                const f32x4 v = acc[m2][nf];
#pragma unroll
                for (int r = 0; r < 4; ++r) {
                    const int tok = tok0 + (m2 << 4) + (hi2 << 2) + r;
                    if (tok < ntok)
                        x16[((size_t)tok << 10) + col] =
                            (unsigned short)bf16_rne(v[r] + bu[nf]);
                }
            }
        }
    }
}

// ---------------------------------------------------------------------------
// K4: rowwise LayerNorm, streaming (r12 proven). One wave per row.
// ---------------------------------------------------------------------------
__global__ __launch_bounds__(256) void k_ln(const unsigned short* __restrict__ x16,
                                            const float* __restrict__ gamma,
                                            const float* __restrict__ beta,
                                            float* __restrict__ out,
                                            int ntok) {
    const int row = (blockIdx.x << 2) + (threadIdx.x >> 6);
    const int l   = threadIdx.x & 63;
    if (row >= ntok) return;

    const unsigned short* xr = x16 + ((size_t)row << 10);
    float v[16];
#pragma unroll
    for (int q = 0; q < 4; ++q) {
        const uint2 u = *(const uint2*)(xr + (q << 8) + (l << 2));
        v[q * 4 + 0] = bf_lo(u.x);
        v[q * 4 + 1] = bf_hi(u.x);
        v[q * 4 + 2] = bf_lo(u.y);
        v[q * 4 + 3] = bf_hi(u.y);
    }
    float s = 0.f, ss = 0.f;
#pragma unroll
    for (int k = 0; k < 16; ++k) { s += v[k]; ss += v[k] * v[k]; }
#pragma unroll
    for (int off = 1; off < 64; off <<= 1) {
        s  += __shfl_xor(s, off);
        ss += __shfl_xor(ss, off);
    }
    const float mu  = s * (1.f / DDIM);
    const float var = ss * (1.f / DDIM) - mu * mu;
    const float inv = rsqrtf(var + LN_EPS);

    float* orow = out + ((size_t)row << 10);
#pragma unroll
    for (int q = 0; q < 4; ++q) {
        const float4 g  = ((const float4*)gamma)[(q << 6) + l];
        const float4 be = ((const float4*)beta)[(q << 6) + l];
        float4 o;
        o.x = (v[q * 4 + 0] - mu) * inv * g.x + be.x;
        o.y = (v[q * 4 + 1] - mu) * inv * g.y + be.y;
        o.z = (v[q * 4 + 2] - mu) * inv * g.z + be.z;
        o.w = (v[q * 4 + 3] - mu) * inv * g.w + be.w;
        ((float4*)orow)[(q << 6) + l] = o;
    }
}

// ---------------------------------------------------------------------------
extern "C" void kernel_launch(void* const* d_in, const int* in_sizes, int n_in,
                              void* d_out, int out_size, void* d_ws, size_t ws_size,
                              hipStream_t stream) {
    const int*   ids   = (const int*)  d_in[0];
    const float* bt    = (const float*)d_in[1];
    const float* pe    = (const float*)d_in[2];
    const float* W     = (const float*)d_in[3];
    const float* b_up  = (const float*)d_in[4];
    const float* gamma = (const float*)d_in[5];
    const float* beta  = (const float*)d_in[6];
    float* out = (float*)d_out;

    const int ntok   = in_sizes[0] / PP;   // B*S = 16384
    const int ntiles = (ntok + 31) / 32;   // 512

    char* ws = (char*)d_ws;
    unsigned short* t2b = (unsigned short*)(ws);              // 2 MB
    uint4*          wbb = (uint4*)(ws + (2  << 20));          // 512 KB (ks-major)
    unsigned short* Abf = (unsigned short*)(ws + (3  << 20)); // 8 MB
    uint2*          Aq  = (uint2*)Abf;
    unsigned short* x16 = (unsigned short*)(ws + (11 << 20)); // 33.5 MB

    hipLaunchKernelGGL(k_prep, dim3(640), dim3(256), 0, stream, bt, pe, W, t2b, wbb);
    hipLaunchKernelGGL(k_gather, dim3((ntok + 3) / 4), dim3(256), 0, stream,
                       ids, t2b, Aq, ntok);
    hipLaunchKernelGGL(k_gemmB, dim3(512), dim3(256), 0, stream,
                       Abf, wbb, b_up, x16, ntok, ntiles);
    hipLaunchKernelGGL(k_ln, dim3((ntok + 3) / 4), dim3(256), 0, stream,
                       x16, gamma, beta, out, ntok);
}